// Round 3
// baseline (236.011 us; speedup 1.0000x reference)
//
#include <hip/hip_runtime.h>

// CRF sequence labeling: B=64, S=512, H=1024, L=9
// Pipeline:
//   K1 logits_kernel : feats[b][s][l] = (inputs[b,s,:]·W[l,:] + bias[l]) * log2(e)
//                      R3: 16-lane groups x 4 rows each (wave = 16 rows) —
//                      one W LDS read feeds 4 rows (9 ds_read_b128/row vs 36);
//                      compute (~18 µs) now fully under the 21 µs HBM floor.
//   K2 chunk_kernel  : per (b, chunk of 32 steps, row i): 9x9 log2-semiring
//                      chunk transfer-matrix row via vector recursion.
//                      Also zeroes d_out (stream-ordered before K3).
//   K3 final_kernel  : per batch: alpha0 ⊗ P_0 ⊗ ... ⊗ P_15, + gold path score;
//                      atomicAdd of (norm-score)*ln2/B into d_out (K4 fused).
// All log-sum-exp math is done in base-2 domain (inputs pre-scaled by log2 e)
// so LSE = max + log2(sum 2^x) uses raw v_exp_f32/v_log_f32.

#define BATCH 64
#define SEQ   512
#define HID   1024
#define NLAB  9
#define CHUNK 32
#define NCHUNK (SEQ / CHUNK)   // 16
#define NREC (BATCH * NCHUNK * NLAB)  // 9216 row recursions

__device__ __forceinline__ float exp2_fast(float x) { return __builtin_amdgcn_exp2f(x); }
__device__ __forceinline__ float log2_fast(float x) { return __builtin_amdgcn_logf(x); }

#define LOG2E 1.4426950408889634f
#define LN2   0.6931471805599453f

// ---------------------------------------------------------------------------
// K1: logits. Grid: (B*S/64) = 512 blocks x 256. Each 16-lane group computes
// 4 rows; wave = 4 groups = 16 rows; block = 64 rows. Per col-chunk of 256,
// lane p covers cols [c*256 + p*16, +16). W read once per label per chunk and
// reused by 4 rows (4 groups read identical addresses -> LDS broadcast).
// W staged in LDS with +1-per-32-floats skew: phys = col + (col>>5); col0 is
// 16-aligned so skew is constant over a lane's 16 cols -> contiguous
// ds_read_b128, bank-spread (measured 0 conflicts in R2 layout).
// ---------------------------------------------------------------------------
__global__ __launch_bounds__(256) void logits_kernel(
    const float* __restrict__ inp, const float* __restrict__ Wg,
    const float* __restrict__ bias, float* __restrict__ feats)
{
    __shared__ float Wl[NLAB * 1056];   // 1024 + 32 skew pad per label row
    const int tid = threadIdx.x;
    for (int i = tid; i < NLAB * HID; i += 256) {
        int l = i >> 10, col = i & 1023;
        Wl[l * 1056 + col + (col >> 5)] = Wg[i];
    }
    __syncthreads();

    const int lane = tid & 63;
    const int wv   = tid >> 6;
    const int p    = lane & 15;      // position within 16-lane group
    const int g    = lane >> 4;      // group within wave
    const long row0 = (long)blockIdx.x * 64 + wv * 16 + g * 4;

    const float* r = inp + row0 * HID;
    float acc[4][NLAB];
    #pragma unroll
    for (int rr = 0; rr < 4; ++rr)
        #pragma unroll
        for (int l = 0; l < NLAB; ++l) acc[rr][l] = 0.f;

    #pragma unroll
    for (int c = 0; c < 4; ++c) {
        const int col0 = c * 256 + p * 16;
        const int sk = col0 + (col0 >> 5);
        float xs[4][16];
        #pragma unroll
        for (int rr = 0; rr < 4; ++rr) {
            const float* rp = r + (long)rr * HID + col0;
            #pragma unroll
            for (int q = 0; q < 4; ++q)
                ((float4*)xs[rr])[q] = ((const float4*)rp)[q];
        }
        #pragma unroll
        for (int l = 0; l < NLAB; ++l) {
            const float* wp = &Wl[l * 1056 + sk];
            float w[16];
            #pragma unroll
            for (int q = 0; q < 4; ++q)
                ((float4*)w)[q] = ((const float4*)wp)[q];
            #pragma unroll
            for (int rr = 0; rr < 4; ++rr) {
                float a = acc[rr][l];
                #pragma unroll
                for (int k = 0; k < 16; ++k) a = fmaf(xs[rr][k], w[k], a);
                acc[rr][l] = a;
            }
        }
    }

    // reduce across the 16-lane group (all 4 groups reduce concurrently)
    #pragma unroll
    for (int rr = 0; rr < 4; ++rr)
        #pragma unroll
        for (int l = 0; l < NLAB; ++l) {
            float a = acc[rr][l];
            a += __shfl_xor(a, 8, 64);
            a += __shfl_xor(a, 4, 64);
            a += __shfl_xor(a, 2, 64);
            a += __shfl_xor(a, 1, 64);
            acc[rr][l] = a;
        }
    if (p == 0) {
        #pragma unroll
        for (int rr = 0; rr < 4; ++rr) {
            float* o = feats + (row0 + rr) * NLAB;
            #pragma unroll
            for (int l = 0; l < NLAB; ++l)
                o[l] = (acc[rr][l] + bias[l]) * LOG2E;
        }
    }
}

// ---------------------------------------------------------------------------
// K2: chunk transfer-matrix rows. Each 9-lane group runs one row recursion:
//   row i of P_c = e_i ⊗ M_ts ⊗ ... ⊗ M_{te-1},  M_t[i][j] = trK[i][j]+emitK[t][j]
// Masked steps contribute the identity (0 diag / -1e30 off-diag).
// 7 groups per wave (63 lanes active). Grid: ceil(9216/7) = 1317 blocks x 64.
// Block 0's idle lane 63 zeroes d_out for K3's atomicAdd (stream-ordered).
// ---------------------------------------------------------------------------
__global__ __launch_bounds__(64) void chunk_kernel(
    const float* __restrict__ feats, const float* __restrict__ trans,
    const int* __restrict__ mask, float* __restrict__ P,
    float* __restrict__ out)
{
    const int lane = threadIdx.x;
    if (blockIdx.x == 0 && lane == 63) out[0] = 0.0f;   // init for K3 atomics
    const int g = lane / 9;
    const int j = lane - g * 9;
    int rid = blockIdx.x * 7 + g;
    bool act = (g < 7) && (rid < NREC);
    if (!act) rid = 0;

    const int i  = rid % NLAB;
    const int bc = rid / NLAB;
    const int c  = bc & (NCHUNK - 1);
    const int b  = bc >> 4;

    float tr[NLAB];
    #pragma unroll
    for (int k = 0; k < NLAB; ++k) tr[k] = trans[k * NLAB + j] * LOG2E;
    const float tri = trans[i * NLAB + j] * LOG2E;  // direct load, no dyn reg index

    const float* fb = feats + (long)b * SEQ * NLAB;
    const int* mb = mask + b * SEQ;
    const int ts = (c == 0) ? 1 : c * CHUNK;
    const int te = (c + 1) * CHUNK;
    const int sbase = g * 9;

    float a;
    {
        int m0 = mb[ts];
        float e0 = fb[ts * NLAB + j];
        float aid = (i == j) ? 0.0f : -1e30f;
        a = (m0 > 0) ? (tri + e0) : aid;
    }

    float e_nxt = fb[(ts + 1) * NLAB + j];
    int   m_nxt = mb[ts + 1];
    for (int t = ts + 1; t < te; ++t) {
        float e = e_nxt;
        int  mt = m_nxt;
        if (t + 1 < te) {               // prefetch next step's emission/mask
            e_nxt = fb[(t + 1) * NLAB + j];
            m_nxt = mb[t + 1];
        }
        float v[NLAB];
        #pragma unroll
        for (int k = 0; k < NLAB; ++k) v[k] = __shfl(a, sbase + k, 64) + tr[k];
        float m01 = fmaxf(v[0], v[1]), m23 = fmaxf(v[2], v[3]);
        float m45 = fmaxf(v[4], v[5]), m67 = fmaxf(v[6], v[7]);
        float mx = fmaxf(fmaxf(fmaxf(m01, m23), fmaxf(m45, m67)), v[8]);
        float s = 0.0f;
        #pragma unroll
        for (int k = 0; k < NLAB; ++k) s += exp2_fast(v[k] - mx);
        float an = mx + log2_fast(s) + e;
        a = (mt > 0) ? an : a;
    }
    if (act) P[(long)rid * NLAB + j] = a;
}

// ---------------------------------------------------------------------------
// K3: per-batch finalize. Grid: 64 blocks x 64.
//  - gold path score (all 64 lanes, strided over t, then wave-reduce)
//  - alpha = alpha0 ⊗ P_0 ⊗ ... ⊗ P_15 (lanes replicate j = lane%9)
//  - atomicAdd of (norm - score)*ln2/B into out[0] (mean fused; device-scope)
// ---------------------------------------------------------------------------
__global__ __launch_bounds__(64) void final_kernel(
    const float* __restrict__ feats, const float* __restrict__ trans,
    const float* __restrict__ startv, const float* __restrict__ endv,
    const int* __restrict__ labels, const int* __restrict__ mask,
    const float* __restrict__ P, float* __restrict__ out)
{
    const int b = blockIdx.x, lane = threadIdx.x;
    const float* fb = feats + (long)b * SEQ * NLAB;
    const int* lb = labels + b * SEQ;
    const int* mb = mask + b * SEQ;

    // ---- gold score ----
    float gsum = 0.0f; int msum = 0;
    for (int t = lane; t < SEQ; t += 64) {
        int tag = lb[t];
        int mt = mb[t];
        if (mt > 0) {
            gsum += fb[t * NLAB + tag];            // feats already *K
            msum++;
            if (t > 0) gsum += trans[lb[t - 1] * NLAB + tag] * LOG2E;
        }
    }
    #pragma unroll
    for (int off = 32; off > 0; off >>= 1) {
        gsum += __shfl_xor(gsum, off, 64);
        msum += __shfl_xor(msum, off, 64);
    }

    // ---- alpha chain over chunk matrices ----
    const int j = lane % 9;      // lanes >=9 replicate; shuffles read lanes 0..8
    float al = fb[j] + startv[j] * LOG2E;
    const float* Pb = P + (long)b * NCHUNK * 81;
    float pc[NLAB];
    #pragma unroll
    for (int i = 0; i < NLAB; ++i) pc[i] = Pb[i * NLAB + j];
    #pragma unroll
    for (int c = 0; c < NCHUNK; ++c) {
        float pn[NLAB];
        if (c < NCHUNK - 1) {
            #pragma unroll
            for (int i = 0; i < NLAB; ++i) pn[i] = Pb[(c + 1) * 81 + i * NLAB + j];
        } else {
            #pragma unroll
            for (int i = 0; i < NLAB; ++i) pn[i] = 0.0f;
        }
        float v[NLAB];
        #pragma unroll
        for (int i = 0; i < NLAB; ++i) v[i] = __shfl(al, i, 64) + pc[i];
        float m01 = fmaxf(v[0], v[1]), m23 = fmaxf(v[2], v[3]);
        float m45 = fmaxf(v[4], v[5]), m67 = fmaxf(v[6], v[7]);
        float mx = fmaxf(fmaxf(fmaxf(m01, m23), fmaxf(m45, m67)), v[8]);
        float s = 0.0f;
        #pragma unroll
        for (int i = 0; i < NLAB; ++i) s += exp2_fast(v[i] - mx);
        al = mx + log2_fast(s);
        #pragma unroll
        for (int i = 0; i < NLAB; ++i) pc[i] = pn[i];
    }
    al += endv[j] * LOG2E;

    // LSE over j (lanes 0..8 hold the distinct values)
    float v[NLAB];
    #pragma unroll
    for (int i = 0; i < NLAB; ++i) v[i] = __shfl(al, i, 64);
    float m01 = fmaxf(v[0], v[1]), m23 = fmaxf(v[2], v[3]);
    float m45 = fmaxf(v[4], v[5]), m67 = fmaxf(v[6], v[7]);
    float mx = fmaxf(fmaxf(fmaxf(m01, m23), fmaxf(m45, m67)), v[8]);
    float s = 0.0f;
    #pragma unroll
    for (int i = 0; i < NLAB; ++i) s += exp2_fast(v[i] - mx);
    float norm = mx + log2_fast(s);

    if (lane == 0) {
        int li = (msum > 0) ? (msum - 1) : 0;
        float score = gsum + startv[lb[0]] * LOG2E + endv[lb[li]] * LOG2E;
        atomicAdd(out, (norm - score) * (LN2 / (float)BATCH));
    }
}

extern "C" void kernel_launch(void* const* d_in, const int* in_sizes, int n_in,
                              void* d_out, int out_size, void* d_ws, size_t ws_size,
                              hipStream_t stream)
{
    const float* inp    = (const float*)d_in[0];
    const int*   labels = (const int*)d_in[1];
    const int*   mask   = (const int*)d_in[2];
    const float* W      = (const float*)d_in[3];
    const float* bias   = (const float*)d_in[4];
    const float* trans  = (const float*)d_in[5];
    const float* startv = (const float*)d_in[6];
    const float* endv   = (const float*)d_in[7];

    float* feats = (float*)d_ws;                    // B*S*L = 294912 floats
    float* P     = feats + BATCH * SEQ * NLAB;      // B*NCHUNK*81 = 82944 floats
    float* out   = (float*)d_out;

    hipLaunchKernelGGL(logits_kernel, dim3(BATCH * SEQ / 64), dim3(256), 0, stream,
                       inp, W, bias, feats);
    hipLaunchKernelGGL(chunk_kernel, dim3((NREC + 6) / 7), dim3(64), 0, stream,
                       feats, trans, mask, P, out);
    hipLaunchKernelGGL(final_kernel, dim3(BATCH), dim3(64), 0, stream,
                       feats, trans, startv, endv, labels, mask, P, out);
}